// Round 8
// baseline (202.586 us; speedup 1.0000x reference)
//
#include <hip/hip_runtime.h>

#define NUM_FEATURES 64
#define MAX_CAV 5
#define NX 704
#define NY 200
#define NUM_PIXELS (NY * NX)             // 140800
#define TOTAL_PIX (MAX_CAV * NUM_PIXELS) // 704000
#define N_PILLARS 60000
#define X4 (NX / 4)                      // 176
#define C_GROUPS 4                       // 64 channels / 16 per thread

typedef float f32x4 __attribute__((ext_vector_type(4)));
typedef int   i32x4 __attribute__((ext_vector_type(4)));

// ---------------------------------------------------------------------------
// Kernel 1: init the pixel->pillar map to -1. Kept despite the 0xAA poison
// (unsigned-compare would reject it) because the FIRST correctness call may
// see un-poisoned (possibly zeroed) d_ws, and 0 is a valid pillar id.
// ---------------------------------------------------------------------------
__global__ void init_map_kernel(int* __restrict__ map) {
    int i = blockIdx.x * blockDim.x + threadIdx.x;       // index into int4 view
    if (i < TOTAL_PIX / 4) {
        i32x4 v = {-1, -1, -1, -1};
        reinterpret_cast<i32x4*>(map)[i] = v;
    }
}

// ---------------------------------------------------------------------------
// Kernel 2: scatter pillar ids into the map. coords layout: [N, 4] = (b,z,y,x),
// read as one int4. Flat indices unique by construction -> plain stores.
// ---------------------------------------------------------------------------
__global__ void scatter_ids_kernel(const int* __restrict__ coords,
                                   int* __restrict__ map) {
    int p = blockIdx.x * blockDim.x + threadIdx.x;
    if (p < N_PILLARS) {
        i32x4 c = reinterpret_cast<const i32x4*>(coords)[p];  // (b, z, y, x)
        map[c.x * NUM_PIXELS + c.z * NX + c.w] = p;
    }
}

// ---------------------------------------------------------------------------
// Kernel 3: output-driven gather. One thread owns 4 consecutive x positions
// x 16 channels. Branchless: invalid pillar ids are clamped to 0 and loaded
// anyway (feat[0]'s line is an L2-resident broadcast), then cndmask-selected
// to zero. All 16 f32x4 loads are issued before any store -> one vmcnt wait
// per thread instead of 8, maximizing memory-level parallelism. 16 NT f32x4
// coalesced stores; every output element written exactly once.
// ---------------------------------------------------------------------------
__global__ void gather_out_kernel(const int* __restrict__ map,
                                  const float* __restrict__ feat,
                                  float* __restrict__ out) {
    const int total_t = MAX_CAV * C_GROUPS * NY * X4;    // 704000
    int t = blockIdx.x * blockDim.x + threadIdx.x;
    if (t >= total_t) return;

    int x4   = t % X4;
    int rest = t / X4;
    int y    = rest % NY;
    rest    /= NY;
    int g    = rest % C_GROUPS;          // channel group -> c0 = g*16
    int b    = rest / C_GROUPS;

    int pix4 = b * (NUM_PIXELS / 4) + y * X4 + x4;
    i32x4 m = reinterpret_cast<const i32x4*>(map)[pix4];
    const int c0 = g * 16;

    bool v0 = (unsigned)m.x < N_PILLARS;
    bool v1 = (unsigned)m.y < N_PILLARS;
    bool v2 = (unsigned)m.z < N_PILLARS;
    bool v3 = (unsigned)m.w < N_PILLARS;
    const float* p0 = feat + (v0 ? m.x : 0) * NUM_FEATURES + c0;
    const float* p1 = feat + (v1 ? m.y : 0) * NUM_FEATURES + c0;
    const float* p2 = feat + (v2 ? m.z : 0) * NUM_FEATURES + c0;
    const float* p3 = feat + (v3 ? m.w : 0) * NUM_FEATURES + c0;

    // issue ALL loads first (contiguous 64B per pixel)
    f32x4 f0[4], f1[4], f2[4], f3[4];
    #pragma unroll
    for (int q = 0; q < 4; ++q) f0[q] = *reinterpret_cast<const f32x4*>(p0 + q * 4);
    #pragma unroll
    for (int q = 0; q < 4; ++q) f1[q] = *reinterpret_cast<const f32x4*>(p1 + q * 4);
    #pragma unroll
    for (int q = 0; q < 4; ++q) f2[q] = *reinterpret_cast<const f32x4*>(p2 + q * 4);
    #pragma unroll
    for (int q = 0; q < 4; ++q) f3[q] = *reinterpret_cast<const f32x4*>(p3 + q * 4);

    const f32x4 z = {0.f, 0.f, 0.f, 0.f};
    #pragma unroll
    for (int q = 0; q < 4; ++q) {
        if (!v0) f0[q] = z;
        if (!v1) f1[q] = z;
        if (!v2) f2[q] = z;
        if (!v3) f3[q] = z;
    }

    // base f32x4 index into out for (b, c0, y, x4); channel stride in f32x4s
    size_t obase = ((size_t)(b * NUM_FEATURES + c0) * NY + y) * X4 + x4;
    const size_t cstride = (size_t)NY * X4;              // 35200
    f32x4* __restrict__ o4 = reinterpret_cast<f32x4*>(out);

    #pragma unroll
    for (int q = 0; q < 4; ++q) {
        size_t ob = obase + (size_t)(q * 4) * cstride;
        f32x4 r0 = {f0[q].x, f1[q].x, f2[q].x, f3[q].x};
        f32x4 r1 = {f0[q].y, f1[q].y, f2[q].y, f3[q].y};
        f32x4 r2 = {f0[q].z, f1[q].z, f2[q].z, f3[q].z};
        f32x4 r3 = {f0[q].w, f1[q].w, f2[q].w, f3[q].w};
        __builtin_nontemporal_store(r0, &o4[ob]);
        __builtin_nontemporal_store(r1, &o4[ob + cstride]);
        __builtin_nontemporal_store(r2, &o4[ob + 2 * cstride]);
        __builtin_nontemporal_store(r3, &o4[ob + 3 * cstride]);
    }
}

extern "C" void kernel_launch(void* const* d_in, const int* in_sizes, int n_in,
                              void* d_out, int out_size, void* d_ws, size_t ws_size,
                              hipStream_t stream) {
    const int*   coords = reinterpret_cast<const int*>(d_in[0]);     // [N,4] int32
    const float* feat   = reinterpret_cast<const float*>(d_in[1]);   // [N,64] f32
    float*       out    = reinterpret_cast<float*>(d_out);           // [5,64,200,704]
    int*         map    = reinterpret_cast<int*>(d_ws);              // 704000 ints

    // 1) map <- -1
    {
        int n = TOTAL_PIX / 4;                 // 176000
        int blocks = (n + 255) / 256;
        init_map_kernel<<<blocks, 256, 0, stream>>>(map);
    }
    // 2) map[pixel] <- pillar id
    {
        int blocks = (N_PILLARS + 255) / 256;
        scatter_ids_kernel<<<blocks, 256, 0, stream>>>(coords, map);
    }
    // 3) coalesced gather into output
    {
        int n = MAX_CAV * C_GROUPS * NY * X4;  // 704000
        int blocks = (n + 255) / 256;          // 2750
        gather_out_kernel<<<blocks, 256, 0, stream>>>(map, feat, out);
    }
}

// Round 9
// 201.862 us; speedup vs baseline: 1.0036x; 1.0036x over previous
//
#include <hip/hip_runtime.h>

#define NUM_FEATURES 64
#define MAX_CAV 5
#define NX 704
#define NY 200
#define NUM_PIXELS (NY * NX)             // 140800
#define TOTAL_PIX (MAX_CAV * NUM_PIXELS) // 704000
#define N_PILLARS 60000
#define X4 (NX / 4)                      // 176
#define C_GROUPS 4                       // 64 channels / 16 per thread

typedef float          f32x4 __attribute__((ext_vector_type(4)));
typedef int            i32x4 __attribute__((ext_vector_type(4)));
typedef unsigned short u16x4 __attribute__((ext_vector_type(4)));

// ---------------------------------------------------------------------------
// Map init is done by hipMemsetAsync(map, 0xFF, ...) in kernel_launch:
// 0xFFFF = 65535 >= N_PILLARS acts as the "empty" sentinel for uint16 ids.
// (Must run every call: d_ws is re-poisoned to 0xAA before every timed launch,
// and 0xAAAA = 43690 would read as a VALID pillar id.)
// ---------------------------------------------------------------------------

// ---------------------------------------------------------------------------
// Kernel 1: scatter pillar ids into the uint16 map. coords: [N,4] = (b,z,y,x),
// read as one int4. Flat indices unique by construction -> plain stores.
// ---------------------------------------------------------------------------
__global__ void scatter_ids_kernel(const int* __restrict__ coords,
                                   unsigned short* __restrict__ map) {
    int p = blockIdx.x * blockDim.x + threadIdx.x;
    if (p < N_PILLARS) {
        i32x4 c = reinterpret_cast<const i32x4*>(coords)[p];  // (b, z, y, x)
        map[c.x * NUM_PIXELS + c.z * NX + c.w] = (unsigned short)p;
    }
}

// ---------------------------------------------------------------------------
// Kernel 2: output-driven gather. One thread owns 4 consecutive x positions
// x 16 channels. Branchless: invalid ids clamp to 0 and load anyway (feat[0]
// line is L2-resident broadcast), then select zero. All 16 f32x4 loads issued
// before any store (one vmcnt wait). 16 NT f32x4 coalesced stores; every
// output element written exactly once -> no 180 MB zeroing pass.
// ---------------------------------------------------------------------------
__global__ void gather_out_kernel(const unsigned short* __restrict__ map,
                                  const float* __restrict__ feat,
                                  float* __restrict__ out) {
    const int total_t = MAX_CAV * C_GROUPS * NY * X4;    // 704000
    int t = blockIdx.x * blockDim.x + threadIdx.x;
    if (t >= total_t) return;

    int x4   = t % X4;
    int rest = t / X4;
    int y    = rest % NY;
    rest    /= NY;
    int g    = rest % C_GROUPS;          // channel group -> c0 = g*16
    int b    = rest / C_GROUPS;

    int pix4 = b * (NUM_PIXELS / 4) + y * X4 + x4;
    u16x4 m = reinterpret_cast<const u16x4*>(map)[pix4];  // 8B aligned
    const int c0 = g * 16;

    int id0 = m.x, id1 = m.y, id2 = m.z, id3 = m.w;      // zero-extended
    bool v0 = id0 < N_PILLARS;
    bool v1 = id1 < N_PILLARS;
    bool v2 = id2 < N_PILLARS;
    bool v3 = id3 < N_PILLARS;
    const float* p0 = feat + (v0 ? id0 : 0) * NUM_FEATURES + c0;
    const float* p1 = feat + (v1 ? id1 : 0) * NUM_FEATURES + c0;
    const float* p2 = feat + (v2 ? id2 : 0) * NUM_FEATURES + c0;
    const float* p3 = feat + (v3 ? id3 : 0) * NUM_FEATURES + c0;

    // issue ALL loads first (contiguous 64B per pixel)
    f32x4 f0[4], f1[4], f2[4], f3[4];
    #pragma unroll
    for (int q = 0; q < 4; ++q) f0[q] = *reinterpret_cast<const f32x4*>(p0 + q * 4);
    #pragma unroll
    for (int q = 0; q < 4; ++q) f1[q] = *reinterpret_cast<const f32x4*>(p1 + q * 4);
    #pragma unroll
    for (int q = 0; q < 4; ++q) f2[q] = *reinterpret_cast<const f32x4*>(p2 + q * 4);
    #pragma unroll
    for (int q = 0; q < 4; ++q) f3[q] = *reinterpret_cast<const f32x4*>(p3 + q * 4);

    const f32x4 z = {0.f, 0.f, 0.f, 0.f};
    #pragma unroll
    for (int q = 0; q < 4; ++q) {
        if (!v0) f0[q] = z;
        if (!v1) f1[q] = z;
        if (!v2) f2[q] = z;
        if (!v3) f3[q] = z;
    }

    // base f32x4 index into out for (b, c0, y, x4); channel stride in f32x4s
    size_t obase = ((size_t)(b * NUM_FEATURES + c0) * NY + y) * X4 + x4;
    const size_t cstride = (size_t)NY * X4;              // 35200
    f32x4* __restrict__ o4 = reinterpret_cast<f32x4*>(out);

    #pragma unroll
    for (int q = 0; q < 4; ++q) {
        size_t ob = obase + (size_t)(q * 4) * cstride;
        f32x4 r0 = {f0[q].x, f1[q].x, f2[q].x, f3[q].x};
        f32x4 r1 = {f0[q].y, f1[q].y, f2[q].y, f3[q].y};
        f32x4 r2 = {f0[q].z, f1[q].z, f2[q].z, f3[q].z};
        f32x4 r3 = {f0[q].w, f1[q].w, f2[q].w, f3[q].w};
        __builtin_nontemporal_store(r0, &o4[ob]);
        __builtin_nontemporal_store(r1, &o4[ob + cstride]);
        __builtin_nontemporal_store(r2, &o4[ob + 2 * cstride]);
        __builtin_nontemporal_store(r3, &o4[ob + 3 * cstride]);
    }
}

extern "C" void kernel_launch(void* const* d_in, const int* in_sizes, int n_in,
                              void* d_out, int out_size, void* d_ws, size_t ws_size,
                              hipStream_t stream) {
    const int*      coords = reinterpret_cast<const int*>(d_in[0]);   // [N,4] int32
    const float*    feat   = reinterpret_cast<const float*>(d_in[1]); // [N,64] f32
    float*          out    = reinterpret_cast<float*>(d_out);         // [5,64,200,704]
    unsigned short* map    = reinterpret_cast<unsigned short*>(d_ws); // 704000 u16

    // 1) map <- 0xFFFF sentinel via runtime fill path (graph-capturable)
    hipMemsetAsync(map, 0xFF, (size_t)TOTAL_PIX * sizeof(unsigned short), stream);

    // 2) map[pixel] <- pillar id
    {
        int blocks = (N_PILLARS + 255) / 256;
        scatter_ids_kernel<<<blocks, 256, 0, stream>>>(coords, map);
    }
    // 3) coalesced gather into output
    {
        int n = MAX_CAV * C_GROUPS * NY * X4;  // 704000
        int blocks = (n + 255) / 256;          // 2750
        gather_out_kernel<<<blocks, 256, 0, stream>>>(map, feat, out);
    }
}